// Round 6
// baseline (95325.458 us; speedup 1.0000x reference)
//
#include <hip/hip_runtime.h>

#define DEVFN __device__ __forceinline__

// tanh(x) = sign(x) * (1 - e^{-2|x|}) / (1 + e^{-2|x|}); exact formula, ~2-3 ulp
DEVFN float fast_tanh(float v) {
    float ax = fabsf(v);
    float t  = __builtin_amdgcn_exp2f(ax * -2.8853900817779268f);  // exp(-2*ax)
    float r  = (1.0f - t) * __builtin_amdgcn_rcpf(1.0f + t);
    return copysignf(r, v);
}

static constexpr int B = 64, U = 4096, H = 64;
static constexpr int N = B * U;  // 262144 sequential steps

// permlane swap builtins return: unsigned int vector of 2 (index with [0]/[1])
typedef unsigned int v2u __attribute__((__vector_size__(2 * sizeof(unsigned int))));

// ============================================================================
// Kernel 1: parallel input projection (unchanged — noise at this scale).
// x'[i][j] = sum_k emb[ids[i]][k] * W_ih[j][k] + b_ih[j] + b_hh[j]
// ============================================================================
__global__ __launch_bounds__(64) void proj_kernel(
    const int*   __restrict__ y,      // [B][U]
    const float* __restrict__ emb,    // [V][H]
    const float* __restrict__ W_ih,   // [H][H]
    const float* __restrict__ b_ih,
    const float* __restrict__ b_hh,
    float*       __restrict__ xout)   // [N][H]
{
    __shared__ __align__(16) float e_s[64][H];
    __shared__ int ids_s[64];
    const int l    = threadIdx.x;          // 0..63
    const int row0 = blockIdx.x * 64;

    float w[H];
    #pragma unroll
    for (int k4 = 0; k4 < 16; ++k4) {
        float4 v = *(const float4*)&W_ih[l * H + k4 * 4];
        w[k4*4+0] = v.x; w[k4*4+1] = v.y; w[k4*4+2] = v.z; w[k4*4+3] = v.w;
    }
    const float bias = b_ih[l] + b_hh[l];

    {
        int i = row0 + l;
        ids_s[l] = y[(i & (B - 1)) * U + (i >> 6)];
    }
    __syncthreads();

    #pragma unroll 4
    for (int r = 0; r < 64; ++r) {
        e_s[r][l] = emb[ids_s[r] * H + l];
    }
    __syncthreads();

    #pragma unroll 1
    for (int r = 0; r < 64; ++r) {
        float acc0 = bias, acc1 = 0.f;
        #pragma unroll
        for (int k4 = 0; k4 < 16; ++k4) {
            float4 ev = *(const float4*)&e_s[r][k4 * 4];
            acc0 = fmaf(ev.x, w[k4*4+0], acc0);
            acc1 = fmaf(ev.y, w[k4*4+1], acc1);
            acc0 = fmaf(ev.z, w[k4*4+2], acc0);
            acc1 = fmaf(ev.w, w[k4*4+3], acc1);
        }
        xout[(row0 + r) * H + l] = acc0 + acc1;
    }
}

// ============================================================================
// Kernel 2: sequential scan, one wave. R6 change: PIN the 64 weights and the
// x-prefetch ring in VGPRs via empty asm ("+v") so the register allocator
// cannot rematerialize their loads inside the loop.
// R5 evidence: VGPR_Count=44 < 64 live weights => RA rematerialized the
// weight gathers every step (L1-hit global loads + waitcnt on the critical
// path), masking the v_fmac_f32_dpp win.
// ============================================================================

// ---- 64 named weights: wB_R = W_hh[j][16*B + ((j - R) & 15)] ----
#define DW(Bk, R) float w##Bk##_##R = W_hh[j * H + (Bk) * 16 + (((j & 15) - (R)) & 15)];
#define DWBLK(Bk) DW(Bk,0) DW(Bk,1) DW(Bk,2) DW(Bk,3) DW(Bk,4) DW(Bk,5) DW(Bk,6) DW(Bk,7) \
                  DW(Bk,8) DW(Bk,9) DW(Bk,10) DW(Bk,11) DW(Bk,12) DW(Bk,13) DW(Bk,14) DW(Bk,15)

// ---- pin a block of 16 weights: defs become asm results (non-remat) ----
#define PIN16(Bk)                                                            \
    asm volatile("" : "+v"(w##Bk##_0),  "+v"(w##Bk##_1),  "+v"(w##Bk##_2),   \
                      "+v"(w##Bk##_3),  "+v"(w##Bk##_4),  "+v"(w##Bk##_5),   \
                      "+v"(w##Bk##_6),  "+v"(w##Bk##_7),  "+v"(w##Bk##_8),   \
                      "+v"(w##Bk##_9),  "+v"(w##Bk##_10), "+v"(w##Bk##_11),  \
                      "+v"(w##Bk##_12), "+v"(w##Bk##_13), "+v"(w##Bk##_14),  \
                      "+v"(w##Bk##_15));

#define PIN(X) asm volatile("" : "+v"(X));

// ---- broadcast h -> 4 block-replicated registers (VALU-only) ----
#define BCAST(h)                                                                     \
    const unsigned hbits = (unsigned)__float_as_int(h);                              \
    v2u p  = __builtin_amdgcn_permlane32_swap(hbits, hbits, false, false);           \
    v2u q0 = __builtin_amdgcn_permlane16_swap(p[0], p[0], false, false);             \
    v2u q1 = __builtin_amdgcn_permlane16_swap(p[1], p[1], false, false);             \
    float hb0 = __int_as_float((int)q0[0]), hb1 = __int_as_float((int)q0[1]);        \
    float hb2 = __int_as_float((int)q1[0]), hb3 = __int_as_float((int)q1[1]);

// ---- fused DPP MAC: acc += rotate16(hb, R) * w   (dst[l] = src[(l-R)&15]) ----
#define FMAC_DPP(ACC, HB, W, R)                                              \
    asm("v_fmac_f32_dpp %0, %1, %2 row_ror:" #R " row_mask:0xf bank_mask:0xf"\
        : "+v"(ACC) : "v"(HB), "v"(W))

// ---- one rotation step: 4 fused fmacs, chains interleaved ----
#define FR(R)                                  \
    FMAC_DPP(acc0, hb0, w0_##R, R);            \
    FMAC_DPP(acc1, hb1, w1_##R, R);            \
    FMAC_DPP(acc2, hb2, w2_##R, R);            \
    FMAC_DPP(acc3, hb3, w3_##R, R);

// ---- one recurrence step; XF is a named register, PFETCH is a statement ----
#define SLOT(XF, IDX, PFETCH) {                                              \
    BCAST(h)                                                                 \
    float acc0 = XF, acc1 = 0.f, acc2 = 0.f, acc3 = 0.f;                     \
    acc0 = fmaf(hb0, w0_0, acc0);  /* plain MACs: also provide >=2-instr */  \
    acc1 = fmaf(hb1, w1_0, acc1);  /* spacing between permlane writes of */  \
    acc2 = fmaf(hb2, w2_0, acc2);  /* hb* and the first DPP read (hazard) */ \
    acc3 = fmaf(hb3, w3_0, acc3);                                            \
    FR(1)  FR(2)  FR(3)  FR(4)  FR(5)  FR(6)  FR(7)                          \
    FR(8)  FR(9)  FR(10) FR(11) FR(12) FR(13) FR(14) FR(15)                  \
    h = fast_tanh((acc0 + acc1) + (acc2 + acc3));                            \
    op[(IDX) * H] = h;                                                       \
    PFETCH                                                                   \
}

__global__ __launch_bounds__(64, 1) void scan_kernel(
    const float* __restrict__ W_hh,   // [H][H]
    const float* __restrict__ h0,     // [H]
    const float* __restrict__ xin,    // [N][H]  (= d_out holding x')
    float*       __restrict__ xout)   // [N][H]  (= d_out, overwritten with h)
{
    const int j = threadIdx.x;        // 0..63

    DWBLK(0) DWBLK(1) DWBLK(2) DWBLK(3)   // 64 scalar weights
    PIN16(0) PIN16(1) PIN16(2) PIN16(3)   // ...forced VGPR-resident

    float h = h0[j];

    const float* xp = xin  + j;       // lane j's element of row 0
    float*       op = xout + j;

    // 8-deep named prefetch ring: rows 0..7 (pinned so refills can't be sunk)
    float x0 = xp[0*H], x1 = xp[1*H], x2 = xp[2*H], x3 = xp[3*H];
    float x4 = xp[4*H], x5 = xp[5*H], x6 = xp[6*H], x7 = xp[7*H];
    PIN(x0) PIN(x1) PIN(x2) PIN(x3) PIN(x4) PIN(x5) PIN(x6) PIN(x7)
    xp += 8 * H;                      // xp now points at row i+8

    #pragma unroll 1
    for (int i = 0; i < N - 8; i += 8) {
        SLOT(x0, 0, x0 = xp[0*H]; PIN(x0))
        SLOT(x1, 1, x1 = xp[1*H]; PIN(x1))
        SLOT(x2, 2, x2 = xp[2*H]; PIN(x2))
        SLOT(x3, 3, x3 = xp[3*H]; PIN(x3))
        SLOT(x4, 4, x4 = xp[4*H]; PIN(x4))
        SLOT(x5, 5, x5 = xp[5*H]; PIN(x5))
        SLOT(x6, 6, x6 = xp[6*H]; PIN(x6))
        SLOT(x7, 7, x7 = xp[7*H]; PIN(x7))
        xp += 8 * H;
        op += 8 * H;
    }
    // epilogue: last 8 rows, no prefetch
    SLOT(x0, 0, ) SLOT(x1, 1, ) SLOT(x2, 2, ) SLOT(x3, 3, )
    SLOT(x4, 4, ) SLOT(x5, 5, ) SLOT(x6, 6, ) SLOT(x7, 7, )
}

// ============================================================================
extern "C" void kernel_launch(void* const* d_in, const int* in_sizes, int n_in,
                              void* d_out, int out_size, void* d_ws, size_t ws_size,
                              hipStream_t stream) {
    const int*   y    = (const int*)  d_in[0];
    const float* emb  = (const float*)d_in[1];
    const float* W_ih = (const float*)d_in[2];
    const float* W_hh = (const float*)d_in[3];
    const float* b_ih = (const float*)d_in[4];
    const float* b_hh = (const float*)d_in[5];
    const float* h0   = (const float*)d_in[6];
    float* out = (float*)d_out;

    // Stage x' directly in d_out; scan overwrites it in place (strict
    // read-before-write per element within the single sequential wave).
    proj_kernel<<<dim3(N / 64), dim3(64), 0, stream>>>(y, emb, W_ih, b_ih, b_hh, out);
    scan_kernel<<<dim3(1), dim3(64), 0, stream>>>(W_hh, h0, out, out);
}